// Round 13
// baseline (269.225 us; speedup 1.0000x reference)
//
#include <hip/hip_runtime.h>
#include <math.h>

#define TT 40          // total query tokens (sum of q_seqlens)
#define NB 16          // batch
#define HQn 16         // query heads
#define HKn 8          // kv heads
#define Gn 2           // GQA group
#define Dn 256         // head dim
#define HID 3072
#define QKV_COLS 8192  // 4096 + 2048 + 2048
#define NPART 64       // 32-token parts per sequence (2048/32)

// intra-wave LDS handoff fence (guide rule #18)
#define WAVE_LDS_FENCE() do { \
    asm volatile("s_waitcnt lgkmcnt(0)" ::: "memory"); \
    __builtin_amdgcn_sched_barrier(0); \
  } while (0)

// ---------------- K1: QKV partial GEMM ----------------
// grid 512 = 32 col-tiles(256) * 16 k-splits(192), block 256
// r6 mapping (10 rows x 4 cols, coalesced W) but h via broadcast ds_read_b128.
__global__ __launch_bounds__(256) void k1_qkv_gemm(
    const float* __restrict__ hs, const float* __restrict__ Wq,
    const float* __restrict__ Wk, const float* __restrict__ Wv,
    float* __restrict__ part1) {
  const int tile = blockIdx.x & 31;
  const int ks = blockIdx.x >> 5;
  const int c0 = tile << 8;
  const float* W; int ld, cw0;
  if (tile < 16)      { W = Wq; ld = 4096; cw0 = c0; }
  else if (tile < 24) { W = Wk; ld = 2048; cw0 = c0 - 4096; }
  else                { W = Wv; ld = 2048; cw0 = c0 - 6144; }
  const int kbase = ks * 192;
  const int cq = (threadIdx.x & 63) << 2;
  const int r0 = (threadIdx.x >> 6) * 10;
  __shared__ float h_lds[40][64];
  float acc[10][4];
#pragma unroll
  for (int r = 0; r < 10; ++r) { acc[r][0]=0.f; acc[r][1]=0.f; acc[r][2]=0.f; acc[r][3]=0.f; }
  for (int kc = 0; kc < 192; kc += 64) {
    __syncthreads();
    for (int i = threadIdx.x; i < 2560; i += 256) {
      int t = i >> 6, kk = i & 63;
      h_lds[t][kk] = hs[t * HID + kbase + kc + kk];
    }
    __syncthreads();
    const float* wp = W + (size_t)(kbase + kc) * ld + cw0 + cq;
#pragma unroll 2
    for (int k4 = 0; k4 < 16; ++k4) {
      float4 h4[10];
#pragma unroll
      for (int r = 0; r < 10; ++r)   // wave-uniform rows -> broadcast b128
        h4[r] = *reinterpret_cast<const float4*>(&h_lds[r0 + r][k4 << 2]);
#pragma unroll
      for (int j = 0; j < 4; ++j) {
        float4 w4 = *reinterpret_cast<const float4*>(wp + (size_t)((k4 << 2) + j) * ld);
#pragma unroll
        for (int r = 0; r < 10; ++r) {
          float hv = (j == 0) ? h4[r].x : (j == 1) ? h4[r].y
                   : (j == 2) ? h4[r].z : h4[r].w;
          acc[r][0] = fmaf(hv, w4.x, acc[r][0]);
          acc[r][1] = fmaf(hv, w4.y, acc[r][1]);
          acc[r][2] = fmaf(hv, w4.z, acc[r][2]);
          acc[r][3] = fmaf(hv, w4.w, acc[r][3]);
        }
      }
    }
  }
#pragma unroll
  for (int r = 0; r < 10; ++r) {
    int t = r0 + r;
    float4 v = make_float4(acc[r][0], acc[r][1], acc[r][2], acc[r][3]);
    *reinterpret_cast<float4*>(&part1[(size_t)(ks * TT + t) * QKV_COLS + c0 + cq]) = v;
  }
}

// ---------------- K2: k-split reduce + RoPE (r6 version) ----------------
// grid 1280 = 40 tokens * 32 tiles, block 256
__global__ __launch_bounds__(256) void k2_reduce_rope(
    const float* __restrict__ part1, const float* __restrict__ inv_freq,
    const int* __restrict__ pos_ids,
    float* __restrict__ qbuf, float* __restrict__ kbuf, float* __restrict__ vbuf) {
  const int t = blockIdx.x >> 5;
  const int tile = blockIdx.x & 31;
  const int c = (tile << 8) + threadIdx.x;
  float s = 0.f;
#pragma unroll
  for (int ks = 0; ks < 16; ++ks) s += part1[(size_t)(ks * TT + t) * QKV_COLS + c];
  __shared__ float sl[256];
  sl[threadIdx.x] = s;
  __syncthreads();
  if (tile < 24) {
    const int d = threadIdx.x;
    const int d2 = d & 127;
    float fr = (float)pos_ids[t] * inv_freq[d2];
    float cs = cosf(fr), sn = sinf(fr);
    float v = (d < 128) ? (sl[d] * cs - sl[d + 128] * sn)
                        : (sl[d] * cs + sl[d - 128] * sn);
    if (tile < 16) qbuf[t * 4096 + (tile << 8) + d] = v * 0.0625f;  // fold 1/sqrt(D)
    else           kbuf[t * 2048 + ((tile - 16) << 8) + d] = v;
  } else {
    vbuf[t * 2048 + ((tile - 24) << 8) + threadIdx.x] = s;
  }
}

// ---------------- K3 v13: 32-token wave-parts, 2x concurrency ----------------
// grid 2048 = b(16)*hk(8)*seg(16); block 256 = 4 waves; wave owns one 32-token
// part (part = seg*4+w; cache block = blk_off[part>>1]). Single score pass with
// 2-deep pipelined K loads. LDS 16.4 KB; no block barriers after Q staging.
__global__ __launch_bounds__(256) void k3_attn_partial(
    const float* __restrict__ qbuf, const float* __restrict__ kbuf,
    const float* __restrict__ vbuf, const float* __restrict__ k_cache,
    const float* __restrict__ v_cache, const int* __restrict__ blk_off,
    const int* __restrict__ q_start, const int* __restrict__ q_lens,
    const int* __restrict__ kv_lens,
    float* __restrict__ part_o, float* __restrict__ part_ml) {
  const int seg = blockIdx.x & 15;
  const int hk = (blockIdx.x >> 4) & 7;
  const int b = blockIdx.x >> 7;
  const int kv_len = kv_lens[b];
  if ((seg << 7) >= kv_len) return;          // block covers tokens [seg*128, ..)
  const int q_cnt = q_lens[b];
  const int hist = kv_len - q_cnt;
  const int q0 = q_start[b];
  const int nq = q_cnt * 2;

  __shared__ float q_lds[8][256];            //  8 KB (block-shared)
  __shared__ float S[4][2][32][8];           //  8 KB (wave-private slices)

  const int tid = threadIdx.x;
  const int w = tid >> 6;
  const int lane = tid & 63;

  for (int i = tid; i < 2048; i += 256) {
    int qv = i >> 8, d = i & 255;
    int qtok = min(qv >> 1, q_cnt - 1);
    q_lds[qv][d] = qbuf[(size_t)(q0 + qtok) * 4096 + (hk * Gn + (qv & 1)) * 256 + d];
  }
  __syncthreads();                           // the ONLY block barrier

  const int part = (seg << 2) + w;           // 0..63, 32 tokens each
  const int sBeg = part << 5;
  if (sBeg >= kv_len) return;                // wave-level exit

  const int blk = blk_off[(b << 5) + (part >> 1)];  // one cache block per part
  const float* kb   = k_cache + ((size_t)blk << 17) + ((size_t)hk << 8);
  const float* vb   = v_cache + ((size_t)blk << 17) + ((size_t)hk << 8);
  const float* knew = kbuf + ((size_t)q0 << 11) + ((size_t)hk << 8);
  const float* vnew = vbuf + ((size_t)q0 << 11) + ((size_t)hk << 8);

  const int tp = lane & 7;
  const int qd = lane >> 3;

  // ---- score: 32 tokens; lane owns 4 tokens x 32 interleaved dims ----
  {
    const float* kr[4];
#pragma unroll
    for (int tt = 0; tt < 4; ++tt) {
      int s = sBeg + (tp << 2) + tt;
      int sc = s < kv_len ? s : kv_len - 1;  // clamp; masked in softmax
      const float* row = (sc < hist) ? (kb + ((size_t)(sc & 63) << 11))
                                     : (knew + ((size_t)(sc - hist) << 11));
      kr[tt] = row + (qd << 2);
    }
    float acc[4][8];
#pragma unroll
    for (int tt = 0; tt < 4; ++tt)
#pragma unroll
      for (int qv = 0; qv < 8; ++qv) acc[tt][qv] = 0.f;

    float4 kf[2][4];
#pragma unroll
    for (int tt = 0; tt < 4; ++tt)
      kf[0][tt] = *reinterpret_cast<const float4*>(kr[tt]);
#pragma unroll
    for (int c = 0; c < 8; ++c) {
      if (c + 1 < 8) {                       // next chunk in flight under FMAs
#pragma unroll
        for (int tt = 0; tt < 4; ++tt)
          kf[(c + 1) & 1][tt] =
              *reinterpret_cast<const float4*>(kr[tt] + ((c + 1) << 5));
      }
      const float4* kc_ = kf[c & 1];
#pragma unroll
      for (int qv = 0; qv < 8; ++qv) {
        float4 qf = *reinterpret_cast<const float4*>(&q_lds[qv][(qd << 2) + (c << 5)]);
#pragma unroll
        for (int tt = 0; tt < 4; ++tt) {
          acc[tt][qv] = fmaf(qf.x, kc_[tt].x, acc[tt][qv]);
          acc[tt][qv] = fmaf(qf.y, kc_[tt].y, acc[tt][qv]);
          acc[tt][qv] = fmaf(qf.z, kc_[tt].z, acc[tt][qv]);
          acc[tt][qv] = fmaf(qf.w, kc_[tt].w, acc[tt][qv]);
        }
      }
    }
#pragma unroll
    for (int tt = 0; tt < 4; ++tt)
#pragma unroll
      for (int qv = 0; qv < 8; ++qv) {
        float v = acc[tt][qv];
        v += __shfl_xor(v, 8);
        v += __shfl_xor(v, 16);
        acc[tt][qv] = v;                     // half-sums at qd=0 (h0), qd=4 (h1)
      }
    if ((lane & 24) == 0) {
      const int h = lane >> 5;
#pragma unroll
      for (int tt = 0; tt < 4; ++tt) {
        int srel = (tp << 2) + tt;
        *reinterpret_cast<float4*>(&S[w][h][srel][0]) =
            make_float4(acc[tt][0], acc[tt][1], acc[tt][2], acc[tt][3]);
        *reinterpret_cast<float4*>(&S[w][h][srel][4]) =
            make_float4(acc[tt][4], acc[tt][5], acc[tt][6], acc[tt][7]);
      }
    }
  }
  WAVE_LDS_FENCE();

  // ---- wave-local softmax over 32 tokens x 8 qv ----
  const int qv2 = lane >> 3;
  const int grp = lane & 7;
  const int pidx8 = (((b * HKn + hk) * NPART + part) << 3);
  float sv[4];
  float mloc = -1e30f;
#pragma unroll
  for (int t = 0; t < 4; ++t) {
    int sl = (t << 3) + grp;
    float v = S[w][0][sl][qv2] + S[w][1][sl][qv2];
    int sAbs = sBeg + sl;
    bool valid = (qv2 < nq) && ((sAbs - hist) <= (qv2 >> 1));  // causal+tail
    v = valid ? v : -1e30f;
    sv[t] = v;
    mloc = fmaxf(mloc, v);
  }
  mloc = fmaxf(mloc, __shfl_xor(mloc, 1));
  mloc = fmaxf(mloc, __shfl_xor(mloc, 2));
  mloc = fmaxf(mloc, __shfl_xor(mloc, 4));
  const float M = mloc;
  float lloc = 0.f;
#pragma unroll
  for (int t = 0; t < 4; ++t) {
    float p = __expf(sv[t] - M);
    S[w][0][(t << 3) + grp][qv2] = p;        // p values in place
    lloc += p;
  }
  lloc += __shfl_xor(lloc, 1);
  lloc += __shfl_xor(lloc, 2);
  lloc += __shfl_xor(lloc, 4);
  if (grp == 0)
    *reinterpret_cast<float2*>(&part_ml[(size_t)(pidx8 + qv2) * 2]) =
        make_float2(M, lloc);
  WAVE_LDS_FENCE();

  // ---- PV: lane owns 4 dims; wave streams its own 32 V rows ----
  const int d4 = lane << 2;
  float4 pacc[8];
#pragma unroll
  for (int q = 0; q < 8; ++q) pacc[q] = make_float4(0.f, 0.f, 0.f, 0.f);
  const int lim = min(sBeg + 32, kv_len);

#define PV_STEP(VROW, SREL)                                          \
  {                                                                  \
    float4 vf = *reinterpret_cast<const float4*>(VROW);              \
    float4 p0 = *reinterpret_cast<const float4*>(&S[w][0][SREL][0]); \
    float4 p1 = *reinterpret_cast<const float4*>(&S[w][0][SREL][4]); \
    float pr[8] = {p0.x, p0.y, p0.z, p0.w, p1.x, p1.y, p1.z, p1.w};  \
    _Pragma("unroll")                                                \
    for (int q = 0; q < 8; ++q) {                                    \
      pacc[q].x = fmaf(pr[q], vf.x, pacc[q].x);                      \
      pacc[q].y = fmaf(pr[q], vf.y, pacc[q].y);                      \
      pacc[q].z = fmaf(pr[q], vf.z, pacc[q].z);                      \
      pacc[q].w = fmaf(pr[q], vf.w, pacc[q].w);                      \
    }                                                                \
  }

  {
    int eH = min(lim, hist);                 // history region (this cache block)
#pragma unroll 4
    for (int s = sBeg; s < eH; ++s)
      PV_STEP(vb + ((size_t)(s & 63) << 11) + d4, s - sBeg);
    int bN = max(sBeg, hist);                // new-token region
    for (int s = bN; s < lim; ++s)
      PV_STEP(vnew + ((size_t)(s - hist) << 11) + d4, s - sBeg);
  }
#undef PV_STEP

#pragma unroll
  for (int q = 0; q < 8; ++q)
    *reinterpret_cast<float4*>(&part_o[(size_t)(pidx8 + q) * 256 + d4]) = pacc[q];
}

// ---------------- K4: combine part partials (up to 64) ----------------
// grid 1024 = b(16)*qtok(4)*h(16), block 64
__global__ __launch_bounds__(64) void k4_attn_reduce(
    const float* __restrict__ part_o, const float* __restrict__ part_ml,
    const int* __restrict__ q_start, const int* __restrict__ q_lens,
    const int* __restrict__ kv_lens, float* __restrict__ attn_out) {
  const int h = blockIdx.x & 15;
  const int qtok = (blockIdx.x >> 4) & 3;
  const int b = blockIdx.x >> 6;
  const int q_cnt = q_lens[b];
  if (qtok >= q_cnt) return;
  const int kv_len = kv_lens[b];
  const int nparts = (kv_len + 31) >> 5;
  const int qv = qtok * 2 + (h & 1);
  const int hk = h >> 1;
  const int lane = threadIdx.x;
  const int pbase = ((b * HKn + hk) * NPART) << 3;
  float M = -1e30f;
#pragma unroll 4
  for (int i = 0; i < nparts; ++i)
    M = fmaxf(M, part_ml[(size_t)(pbase + (i << 3) + qv) * 2]);
  float4 o = make_float4(0.f, 0.f, 0.f, 0.f);
  float L = 0.f;
#pragma unroll 4
  for (int i = 0; i < nparts; ++i) {
    float2 ml = *reinterpret_cast<const float2*>(
        &part_ml[(size_t)(pbase + (i << 3) + qv) * 2]);
    float corr = __expf(ml.x - M);
    L += corr * ml.y;
    float4 pv = *reinterpret_cast<const float4*>(
        &part_o[(size_t)(pbase + (i << 3) + qv) * 256 + (lane << 2)]);
    o.x = fmaf(corr, pv.x, o.x);
    o.y = fmaf(corr, pv.y, o.y);
    o.z = fmaf(corr, pv.z, o.z);
    o.w = fmaf(corr, pv.w, o.w);
  }
  float inv = 1.0f / L;
  int tr = q_start[b] + qtok;
  float4 res = make_float4(o.x * inv, o.y * inv, o.z * inv, o.w * inv);
  *reinterpret_cast<float4*>(&attn_out[((size_t)tr * HQn + h) * 256 + (lane << 2)]) = res;
}

// ---------------- K5: output GEMM partial ----------------
// grid 384 = 12 col-tiles(256) * 32 k-splits(128), block 256; b128 h reads
__global__ __launch_bounds__(256) void k5_out_gemm(
    const float* __restrict__ ain, const float* __restrict__ Wo,
    float* __restrict__ part2) {
  const int tile = blockIdx.x % 12;
  const int ks = blockIdx.x / 12;
  const int c0 = tile << 8;
  const int kbase = ks << 7;
  const int cq = (threadIdx.x & 63) << 2;
  const int r0 = (threadIdx.x >> 6) * 10;
  __shared__ float h_lds[40][64];
  float acc[10][4];
#pragma unroll
  for (int r = 0; r < 10; ++r) { acc[r][0]=0.f; acc[r][1]=0.f; acc[r][2]=0.f; acc[r][3]=0.f; }
  for (int kc = 0; kc < 128; kc += 64) {
    __syncthreads();
    for (int i = threadIdx.x; i < 2560; i += 256) {
      int t = i >> 6, kk = i & 63;
      h_lds[t][kk] = ain[(size_t)t * 4096 + kbase + kc + kk];
    }
    __syncthreads();
    const float* wp = Wo + (size_t)(kbase + kc) * 3072 + c0 + cq;
#pragma unroll 2
    for (int k4 = 0; k4 < 16; ++k4) {
      float4 h4[10];
#pragma unroll
      for (int r = 0; r < 10; ++r)
        h4[r] = *reinterpret_cast<const float4*>(&h_lds[r0 + r][k4 << 2]);
#pragma unroll
      for (int j = 0; j < 4; ++j) {
        float4 w4 = *reinterpret_cast<const float4*>(wp + (size_t)((k4 << 2) + j) * 3072);
#pragma unroll
        for (int r = 0; r < 10; ++r) {
          float hv = (j == 0) ? h4[r].x : (j == 1) ? h4[r].y
                   : (j == 2) ? h4[r].z : h4[r].w;
          acc[r][0] = fmaf(hv, w4.x, acc[r][0]);
          acc[r][1] = fmaf(hv, w4.y, acc[r][1]);
          acc[r][2] = fmaf(hv, w4.z, acc[r][2]);
          acc[r][3] = fmaf(hv, w4.w, acc[r][3]);
        }
      }
    }
  }
#pragma unroll
  for (int r = 0; r < 10; ++r) {
    int t = r0 + r;
    float4 v = make_float4(acc[r][0], acc[r][1], acc[r][2], acc[r][3]);
    *reinterpret_cast<float4*>(&part2[(size_t)(ks * TT + t) * 3072 + c0 + cq]) = v;
  }
}

// ---------------- K6: final k-split reduce -> d_out ----------------
// grid 480, block 256  (40*3072 = 122880 outputs)
__global__ __launch_bounds__(256) void k6_final_reduce(
    const float* __restrict__ part2, float* __restrict__ out) {
  const int idx = blockIdx.x * 256 + threadIdx.x;
  float s = 0.f;
#pragma unroll
  for (int ks = 0; ks < 32; ++ks) s += part2[(size_t)ks * 122880 + idx];
  out[idx] = s;
}

extern "C" void kernel_launch(void* const* d_in, const int* in_sizes, int n_in,
                              void* d_out, int out_size, void* d_ws, size_t ws_size,
                              hipStream_t stream) {
  const float* hs       = (const float*)d_in[0];
  const float* Wq       = (const float*)d_in[1];
  const float* Wk       = (const float*)d_in[2];
  const float* Wv       = (const float*)d_in[3];
  const float* Wo       = (const float*)d_in[4];
  const float* k_cache  = (const float*)d_in[5];
  const float* v_cache  = (const float*)d_in[6];
  const float* inv_freq = (const float*)d_in[7];
  const int*   pos_ids  = (const int*)d_in[8];
  const int*   q_start  = (const int*)d_in[9];
  const int*   q_lens   = (const int*)d_in[10];
  const int*   kv_lens  = (const int*)d_in[11];
  const int*   blk_off  = (const int*)d_in[12];

  float* ws = (float*)d_ws;
  float* qbuf     = ws;                  // 163,840
  float* kbuf     = ws + 163840;         //  81,920
  float* vbuf     = ws + 245760;         //  81,920
  float* attn_out = ws + 327680;         // 163,840
  float* part1    = ws + 491520;         // 5,242,880   (k1/k2 only)
  float* part_o   = ws + 5734400;        // 16,777,216  (128*64*8*256)
  float* part_ml  = ws + 22511616;       //    131,072
  float* part2    = ws + 22642688;       // 3,932,160   (k5/k6)
  float* out      = (float*)d_out;

  k1_qkv_gemm<<<512, 256, 0, stream>>>(hs, Wq, Wk, Wv, part1);
  k2_reduce_rope<<<1280, 256, 0, stream>>>(part1, inv_freq, pos_ids, qbuf, kbuf, vbuf);
  k3_attn_partial<<<2048, 256, 0, stream>>>(qbuf, kbuf, vbuf, k_cache, v_cache,
                                            blk_off, q_start, q_lens, kv_lens,
                                            part_o, part_ml);
  k4_attn_reduce<<<1024, 64, 0, stream>>>(part_o, part_ml, q_start, q_lens,
                                          kv_lens, attn_out);
  k5_out_gemm<<<384, 256, 0, stream>>>(attn_out, Wo, part2);
  k6_final_reduce<<<480, 256, 0, stream>>>(part2, out);
}

// Round 14
// 254.747 us; speedup vs baseline: 1.0568x; 1.0568x over previous
//
#include <hip/hip_runtime.h>
#include <math.h>

#define TT 40          // total query tokens (sum of q_seqlens)
#define NB 16          // batch
#define HQn 16         // query heads
#define HKn 8          // kv heads
#define Gn 2           // GQA group
#define Dn 256         // head dim
#define HID 3072
#define QKV_COLS 8192  // 4096 + 2048 + 2048
#define NPART 32       // 64-token parts per sequence (2048/64)

// intra-wave LDS handoff fence (guide rule #18)
#define WAVE_LDS_FENCE() do { \
    asm volatile("s_waitcnt lgkmcnt(0)" ::: "memory"); \
    __builtin_amdgcn_sched_barrier(0); \
  } while (0)

// ---------------- K1: QKV partial GEMM (r12 version) ----------------
// grid 512 = 32 col-tiles(256) * 16 k-splits(192), block 256
__global__ __launch_bounds__(256) void k1_qkv_gemm(
    const float* __restrict__ hs, const float* __restrict__ Wq,
    const float* __restrict__ Wk, const float* __restrict__ Wv,
    float* __restrict__ part1) {
  const int tile = blockIdx.x & 31;
  const int ks = blockIdx.x >> 5;
  const int c0 = tile << 8;
  const float* W; int ld, cw0;
  if (tile < 16)      { W = Wq; ld = 4096; cw0 = c0; }
  else if (tile < 24) { W = Wk; ld = 2048; cw0 = c0 - 4096; }
  else                { W = Wv; ld = 2048; cw0 = c0 - 6144; }
  const int kbase = ks * 192;
  const int cq = (threadIdx.x & 63) << 2;
  const int r0 = (threadIdx.x >> 6) * 10;
  __shared__ float h_lds[40][64];
  float acc[10][4];
#pragma unroll
  for (int r = 0; r < 10; ++r) { acc[r][0]=0.f; acc[r][1]=0.f; acc[r][2]=0.f; acc[r][3]=0.f; }
  for (int kc = 0; kc < 192; kc += 64) {
    __syncthreads();
    for (int i = threadIdx.x; i < 2560; i += 256) {
      int t = i >> 6, kk = i & 63;
      h_lds[t][kk] = hs[t * HID + kbase + kc + kk];
    }
    __syncthreads();
    const float* wp = W + (size_t)(kbase + kc) * ld + cw0 + cq;
#pragma unroll 2
    for (int k4 = 0; k4 < 16; ++k4) {
      float4 h4[10];
#pragma unroll
      for (int r = 0; r < 10; ++r)
        h4[r] = *reinterpret_cast<const float4*>(&h_lds[r0 + r][k4 << 2]);
#pragma unroll
      for (int j = 0; j < 4; ++j) {
        float4 w4 = *reinterpret_cast<const float4*>(wp + (size_t)((k4 << 2) + j) * ld);
#pragma unroll
        for (int r = 0; r < 10; ++r) {
          float hv = (j == 0) ? h4[r].x : (j == 1) ? h4[r].y
                   : (j == 2) ? h4[r].z : h4[r].w;
          acc[r][0] = fmaf(hv, w4.x, acc[r][0]);
          acc[r][1] = fmaf(hv, w4.y, acc[r][1]);
          acc[r][2] = fmaf(hv, w4.z, acc[r][2]);
          acc[r][3] = fmaf(hv, w4.w, acc[r][3]);
        }
      }
    }
  }
#pragma unroll
  for (int r = 0; r < 10; ++r) {
    int t = r0 + r;
    float4 v = make_float4(acc[r][0], acc[r][1], acc[r][2], acc[r][3]);
    *reinterpret_cast<float4*>(&part1[(size_t)(ks * TT + t) * QKV_COLS + c0 + cq]) = v;
  }
}

// ---------------- K2: k-split reduce + RoPE (r12 version) ----------------
// grid 1280 = 40 tokens * 32 tiles, block 256
__global__ __launch_bounds__(256) void k2_reduce_rope(
    const float* __restrict__ part1, const float* __restrict__ inv_freq,
    const int* __restrict__ pos_ids,
    float* __restrict__ qbuf, float* __restrict__ kbuf, float* __restrict__ vbuf) {
  const int t = blockIdx.x >> 5;
  const int tile = blockIdx.x & 31;
  const int c = (tile << 8) + threadIdx.x;
  float s = 0.f;
#pragma unroll
  for (int ks = 0; ks < 16; ++ks) s += part1[(size_t)(ks * TT + t) * QKV_COLS + c];
  __shared__ float sl[256];
  sl[threadIdx.x] = s;
  __syncthreads();
  if (tile < 24) {
    const int d = threadIdx.x;
    const int d2 = d & 127;
    float fr = (float)pos_ids[t] * inv_freq[d2];
    float cs = cosf(fr), sn = sinf(fr);
    float v = (d < 128) ? (sl[d] * cs - sl[d + 128] * sn)
                        : (sl[d] * cs + sl[d - 128] * sn);
    if (tile < 16) qbuf[t * 4096 + (tile << 8) + d] = v * 0.0625f;  // fold 1/sqrt(D)
    else           kbuf[t * 2048 + ((tile - 16) << 8) + d] = v;
  } else {
    vbuf[t * 2048 + ((tile - 24) << 8) + threadIdx.x] = s;
  }
}

// ---------------- K3 v14: block = (b, cache-block), wave = hk ----------------
// 8 waves (512 threads) each handle one kv-head over the SAME 64-token cache
// block -> the block collectively streams the full 512KB K extent and 512KB V
// extent sequentially (slot-major layout [slk][hk][256]). Per-wave work is
// byte-identical to r12. LDS 80KB -> 2 blocks/CU (16 waves, same as r12):
// single variable = DRAM access pattern. grid 512 = b(16)*part(32).
__global__ __launch_bounds__(512) void k3_attn_partial(
    const float* __restrict__ qbuf, const float* __restrict__ kbuf,
    const float* __restrict__ vbuf, const float* __restrict__ k_cache,
    const float* __restrict__ v_cache, const int* __restrict__ blk_off,
    const int* __restrict__ q_start, const int* __restrict__ q_lens,
    const int* __restrict__ kv_lens,
    float* __restrict__ part_o, float* __restrict__ part_ml) {
  const int part = blockIdx.x & 31;
  const int b = blockIdx.x >> 5;
  const int kv_len = kv_lens[b];
  const int sBeg = part << 6;
  if (sBeg >= kv_len) return;
  const int q_cnt = q_lens[b];
  const int hist = kv_len - q_cnt;
  const int q0 = q_start[b];
  const int nq = q_cnt * 2;

  __shared__ float q_lds[4][16][256];   // 64 KB [qtok][head][d]
  __shared__ float S[8][64][8];         // 16 KB [hk][token][qv]

  const int tid = threadIdx.x;
  const int hk = tid >> 6;              // wave = kv head
  const int lane = tid & 63;

  // stage Q (scale folded): q_cnt * 16 heads * 256
  const int qtot = q_cnt << 12;
  for (int i = tid; i < qtot; i += 512) {
    int qtok = i >> 12;
    int rem = i & 4095;
    q_lds[qtok][rem >> 8][rem & 255] = qbuf[(size_t)(q0 + qtok) * 4096 + rem];
  }
  __syncthreads();                      // the ONLY block barrier

  const int blk = blk_off[(b << 5) + part];
  const float* kb   = k_cache + ((size_t)blk << 17) + ((size_t)hk << 8);
  const float* vb   = v_cache + ((size_t)blk << 17) + ((size_t)hk << 8);
  const float* knew = kbuf + ((size_t)q0 << 11) + ((size_t)hk << 8);
  const float* vnew = vbuf + ((size_t)q0 << 11) + ((size_t)hk << 8);

  const int tp = lane & 7;
  const int qd = lane >> 3;
  const int qc1 = q_cnt - 1;

  // ---- score: 2 passes x 32 tokens; 2-deep pipelined K loads ----
#pragma unroll
  for (int pass = 0; pass < 2; ++pass) {
    const float* kr[4];
#pragma unroll
    for (int tt = 0; tt < 4; ++tt) {
      int s = sBeg + (pass << 5) + (tp << 2) + tt;
      int sc = s < kv_len ? s : kv_len - 1;   // clamp; masked in softmax
      const float* row = (sc < hist) ? (kb + ((size_t)(sc & 63) << 11))
                                     : (knew + ((size_t)(sc - hist) << 11));
      kr[tt] = row + (qd << 2);
    }
    float acc[4][8];
#pragma unroll
    for (int tt = 0; tt < 4; ++tt)
#pragma unroll
      for (int qv = 0; qv < 8; ++qv) acc[tt][qv] = 0.f;

    float4 kf[2][4];
#pragma unroll
    for (int tt = 0; tt < 4; ++tt)
      kf[0][tt] = *reinterpret_cast<const float4*>(kr[tt]);
#pragma unroll
    for (int c = 0; c < 8; ++c) {
      if (c + 1 < 8) {                        // next chunk in flight under FMAs
#pragma unroll
        for (int tt = 0; tt < 4; ++tt)
          kf[(c + 1) & 1][tt] =
              *reinterpret_cast<const float4*>(kr[tt] + ((c + 1) << 5));
      }
      const float4* kc_ = kf[c & 1];
#pragma unroll
      for (int qv = 0; qv < 8; ++qv) {
        int qtok = min(qv >> 1, qc1);
        int head = (hk << 1) + (qv & 1);
        float4 qf = *reinterpret_cast<const float4*>(
            &q_lds[qtok][head][(qd << 2) + (c << 5)]);
#pragma unroll
        for (int tt = 0; tt < 4; ++tt) {
          acc[tt][qv] = fmaf(qf.x, kc_[tt].x, acc[tt][qv]);
          acc[tt][qv] = fmaf(qf.y, kc_[tt].y, acc[tt][qv]);
          acc[tt][qv] = fmaf(qf.z, kc_[tt].z, acc[tt][qv]);
          acc[tt][qv] = fmaf(qf.w, kc_[tt].w, acc[tt][qv]);
        }
      }
    }
#pragma unroll
    for (int tt = 0; tt < 4; ++tt)
#pragma unroll
      for (int qv = 0; qv < 8; ++qv) {
        float v = acc[tt][qv];
        v += __shfl_xor(v, 8);
        v += __shfl_xor(v, 16);
        v += __shfl_xor(v, 32);               // full dot in every lane
        acc[tt][qv] = v;
      }
    if (lane < 8) {                           // qd == 0 lanes store
#pragma unroll
      for (int tt = 0; tt < 4; ++tt) {
        int srel = (pass << 5) + (tp << 2) + tt;
        *reinterpret_cast<float4*>(&S[hk][srel][0]) =
            make_float4(acc[tt][0], acc[tt][1], acc[tt][2], acc[tt][3]);
        *reinterpret_cast<float4*>(&S[hk][srel][4]) =
            make_float4(acc[tt][4], acc[tt][5], acc[tt][6], acc[tt][7]);
      }
    }
  }
  WAVE_LDS_FENCE();

  // ---- wave-local softmax over 64 tokens x 8 qv ----
  const int qv2 = lane >> 3;
  const int grp = lane & 7;
  const int pidx8 = (((b * HKn + hk) * NPART + part) << 3);
  float sv[8];
  float mloc = -1e30f;
#pragma unroll
  for (int t = 0; t < 8; ++t) {
    int sl = (t << 3) + grp;
    float v = S[hk][sl][qv2];
    int sAbs = sBeg + sl;
    bool valid = (qv2 < nq) && ((sAbs - hist) <= (qv2 >> 1));  // causal+tail
    v = valid ? v : -1e30f;
    sv[t] = v;
    mloc = fmaxf(mloc, v);
  }
  mloc = fmaxf(mloc, __shfl_xor(mloc, 1));
  mloc = fmaxf(mloc, __shfl_xor(mloc, 2));
  mloc = fmaxf(mloc, __shfl_xor(mloc, 4));
  const float M = mloc;
  float lloc = 0.f;
#pragma unroll
  for (int t = 0; t < 8; ++t) {
    float p = __expf(sv[t] - M);
    S[hk][(t << 3) + grp][qv2] = p;           // p values in place
    lloc += p;
  }
  lloc += __shfl_xor(lloc, 1);
  lloc += __shfl_xor(lloc, 2);
  lloc += __shfl_xor(lloc, 4);
  if (grp == 0)
    *reinterpret_cast<float2*>(&part_ml[(size_t)(pidx8 + qv2) * 2]) =
        make_float2(M, lloc);
  WAVE_LDS_FENCE();

  // ---- PV: lane owns 4 dims; wave streams its own 64 V rows ----
  const int d4 = lane << 2;
  float4 pacc[8];
#pragma unroll
  for (int q = 0; q < 8; ++q) pacc[q] = make_float4(0.f, 0.f, 0.f, 0.f);
  const int lim = min(sBeg + 64, kv_len);

#define PV_STEP(VROW, SREL)                                          \
  {                                                                  \
    float4 vf = *reinterpret_cast<const float4*>(VROW);              \
    float4 p0 = *reinterpret_cast<const float4*>(&S[hk][SREL][0]);   \
    float4 p1 = *reinterpret_cast<const float4*>(&S[hk][SREL][4]);   \
    float pr[8] = {p0.x, p0.y, p0.z, p0.w, p1.x, p1.y, p1.z, p1.w};  \
    _Pragma("unroll")                                                \
    for (int q = 0; q < 8; ++q) {                                    \
      pacc[q].x = fmaf(pr[q], vf.x, pacc[q].x);                      \
      pacc[q].y = fmaf(pr[q], vf.y, pacc[q].y);                      \
      pacc[q].z = fmaf(pr[q], vf.z, pacc[q].z);                      \
      pacc[q].w = fmaf(pr[q], vf.w, pacc[q].w);                      \
    }                                                                \
  }

  {
    int eH = min(lim, hist);                  // history region (this cache block)
#pragma unroll 4
    for (int s = sBeg; s < eH; ++s)
      PV_STEP(vb + ((size_t)(s & 63) << 11) + d4, s - sBeg);
    int bN = max(sBeg, hist);                 // new-token region
    for (int s = bN; s < lim; ++s)
      PV_STEP(vnew + ((size_t)(s - hist) << 11) + d4, s - sBeg);
  }
#undef PV_STEP

#pragma unroll
  for (int q = 0; q < 8; ++q)
    if (q < nq)                               // wave-uniform; skip dead partials
      *reinterpret_cast<float4*>(&part_o[(size_t)(pidx8 + q) * 256 + d4]) = pacc[q];
}

// ---------------- K4: combine part partials (up to 32, r12 version) ----------
// grid 1024 = b(16)*qtok(4)*h(16), block 64
__global__ __launch_bounds__(64) void k4_attn_reduce(
    const float* __restrict__ part_o, const float* __restrict__ part_ml,
    const int* __restrict__ q_start, const int* __restrict__ q_lens,
    const int* __restrict__ kv_lens, float* __restrict__ attn_out) {
  const int h = blockIdx.x & 15;
  const int qtok = (blockIdx.x >> 4) & 3;
  const int b = blockIdx.x >> 6;
  const int q_cnt = q_lens[b];
  if (qtok >= q_cnt) return;
  const int kv_len = kv_lens[b];
  const int nparts = (kv_len + 63) >> 6;
  const int qv = qtok * 2 + (h & 1);
  const int hk = h >> 1;
  const int lane = threadIdx.x;
  const int pbase = ((b * HKn + hk) * NPART) << 3;
  float M = -1e30f;
#pragma unroll 4
  for (int i = 0; i < nparts; ++i)
    M = fmaxf(M, part_ml[(size_t)(pbase + (i << 3) + qv) * 2]);
  float4 o = make_float4(0.f, 0.f, 0.f, 0.f);
  float L = 0.f;
#pragma unroll 4
  for (int i = 0; i < nparts; ++i) {
    float2 ml = *reinterpret_cast<const float2*>(
        &part_ml[(size_t)(pbase + (i << 3) + qv) * 2]);
    float corr = __expf(ml.x - M);
    L += corr * ml.y;
    float4 pv = *reinterpret_cast<const float4*>(
        &part_o[(size_t)(pbase + (i << 3) + qv) * 256 + (lane << 2)]);
    o.x = fmaf(corr, pv.x, o.x);
    o.y = fmaf(corr, pv.y, o.y);
    o.z = fmaf(corr, pv.z, o.z);
    o.w = fmaf(corr, pv.w, o.w);
  }
  float inv = 1.0f / L;
  int tr = q_start[b] + qtok;
  float4 res = make_float4(o.x * inv, o.y * inv, o.z * inv, o.w * inv);
  *reinterpret_cast<float4*>(&attn_out[((size_t)tr * HQn + h) * 256 + (lane << 2)]) = res;
}

// ---------------- K5: output GEMM partial (r12 version) ----------------
// grid 384 = 12 col-tiles(256) * 32 k-splits(128), block 256; b128 h reads
__global__ __launch_bounds__(256) void k5_out_gemm(
    const float* __restrict__ ain, const float* __restrict__ Wo,
    float* __restrict__ part2) {
  const int tile = blockIdx.x % 12;
  const int ks = blockIdx.x / 12;
  const int c0 = tile << 8;
  const int kbase = ks << 7;
  const int cq = (threadIdx.x & 63) << 2;
  const int r0 = (threadIdx.x >> 6) * 10;
  __shared__ float h_lds[40][64];
  float acc[10][4];
#pragma unroll
  for (int r = 0; r < 10; ++r) { acc[r][0]=0.f; acc[r][1]=0.f; acc[r][2]=0.f; acc[r][3]=0.f; }
  for (int kc = 0; kc < 128; kc += 64) {
    __syncthreads();
    for (int i = threadIdx.x; i < 2560; i += 256) {
      int t = i >> 6, kk = i & 63;
      h_lds[t][kk] = ain[(size_t)t * 4096 + kbase + kc + kk];
    }
    __syncthreads();
    const float* wp = Wo + (size_t)(kbase + kc) * 3072 + c0 + cq;
#pragma unroll 2
    for (int k4 = 0; k4 < 16; ++k4) {
      float4 h4[10];
#pragma unroll
      for (int r = 0; r < 10; ++r)
        h4[r] = *reinterpret_cast<const float4*>(&h_lds[r0 + r][k4 << 2]);
#pragma unroll
      for (int j = 0; j < 4; ++j) {
        float4 w4 = *reinterpret_cast<const float4*>(wp + (size_t)((k4 << 2) + j) * 3072);
#pragma unroll
        for (int r = 0; r < 10; ++r) {
          float hv = (j == 0) ? h4[r].x : (j == 1) ? h4[r].y
                   : (j == 2) ? h4[r].z : h4[r].w;
          acc[r][0] = fmaf(hv, w4.x, acc[r][0]);
          acc[r][1] = fmaf(hv, w4.y, acc[r][1]);
          acc[r][2] = fmaf(hv, w4.z, acc[r][2]);
          acc[r][3] = fmaf(hv, w4.w, acc[r][3]);
        }
      }
    }
  }
#pragma unroll
  for (int r = 0; r < 10; ++r) {
    int t = r0 + r;
    float4 v = make_float4(acc[r][0], acc[r][1], acc[r][2], acc[r][3]);
    *reinterpret_cast<float4*>(&part2[(size_t)(ks * TT + t) * 3072 + c0 + cq]) = v;
  }
}

// ---------------- K6: final k-split reduce -> d_out ----------------
// grid 480, block 256  (40*3072 = 122880 outputs)
__global__ __launch_bounds__(256) void k6_final_reduce(
    const float* __restrict__ part2, float* __restrict__ out) {
  const int idx = blockIdx.x * 256 + threadIdx.x;
  float s = 0.f;
#pragma unroll
  for (int ks = 0; ks < 32; ++ks) s += part2[(size_t)ks * 122880 + idx];
  out[idx] = s;
}

extern "C" void kernel_launch(void* const* d_in, const int* in_sizes, int n_in,
                              void* d_out, int out_size, void* d_ws, size_t ws_size,
                              hipStream_t stream) {
  const float* hs       = (const float*)d_in[0];
  const float* Wq       = (const float*)d_in[1];
  const float* Wk       = (const float*)d_in[2];
  const float* Wv       = (const float*)d_in[3];
  const float* Wo       = (const float*)d_in[4];
  const float* k_cache  = (const float*)d_in[5];
  const float* v_cache  = (const float*)d_in[6];
  const float* inv_freq = (const float*)d_in[7];
  const int*   pos_ids  = (const int*)d_in[8];
  const int*   q_start  = (const int*)d_in[9];
  const int*   q_lens   = (const int*)d_in[10];
  const int*   kv_lens  = (const int*)d_in[11];
  const int*   blk_off  = (const int*)d_in[12];

  float* ws = (float*)d_ws;
  float* qbuf     = ws;                  // 163,840
  float* kbuf     = ws + 163840;         //  81,920
  float* vbuf     = ws + 245760;         //  81,920
  float* attn_out = ws + 327680;         // 163,840
  float* part1    = ws + 491520;         // 5,242,880  (k1/k2 only)
  float* part_o   = ws + 5734400;        // 8,388,608  (128*32*8*256)
  float* part_ml  = ws + 14123008;       //    65,536
  float* part2    = ws + 14188544;       // 3,932,160  (k5/k6)
  float* out      = (float*)d_out;

  k1_qkv_gemm<<<512, 256, 0, stream>>>(hs, Wq, Wk, Wv, part1);
  k2_reduce_rope<<<1280, 256, 0, stream>>>(part1, inv_freq, pos_ids, qbuf, kbuf, vbuf);
  k3_attn_partial<<<512, 512, 0, stream>>>(qbuf, kbuf, vbuf, k_cache, v_cache,
                                           blk_off, q_start, q_lens, kv_lens,
                                           part_o, part_ml);
  k4_attn_reduce<<<1024, 64, 0, stream>>>(part_o, part_ml, q_start, q_lens,
                                          kv_lens, attn_out);
  k5_out_gemm<<<384, 256, 0, stream>>>(attn_out, Wo, part2);
  k6_final_reduce<<<480, 256, 0, stream>>>(part2, out);
}

// Round 15
// 248.605 us; speedup vs baseline: 1.0829x; 1.0247x over previous
//
#include <hip/hip_runtime.h>
#include <math.h>

#define TT 40          // total query tokens (sum of q_seqlens)
#define NB 16          // batch
#define HQn 16         // query heads
#define HKn 8          // kv heads
#define Gn 2           // GQA group
#define Dn 256         // head dim
#define HID 3072
#define QKV_COLS 8192  // 4096 + 2048 + 2048
#define NPART 32       // 64-token parts per sequence (2048/64)

// intra-wave LDS handoff fence (guide rule #18)
#define WAVE_LDS_FENCE() do { \
    asm volatile("s_waitcnt lgkmcnt(0)" ::: "memory"); \
    __builtin_amdgcn_sched_barrier(0); \
  } while (0)

// ---------------- K1: QKV partial GEMM (r12 version) ----------------
// grid 512 = 32 col-tiles(256) * 16 k-splits(192), block 256
__global__ __launch_bounds__(256) void k1_qkv_gemm(
    const float* __restrict__ hs, const float* __restrict__ Wq,
    const float* __restrict__ Wk, const float* __restrict__ Wv,
    float* __restrict__ part1) {
  const int tile = blockIdx.x & 31;
  const int ks = blockIdx.x >> 5;
  const int c0 = tile << 8;
  const float* W; int ld, cw0;
  if (tile < 16)      { W = Wq; ld = 4096; cw0 = c0; }
  else if (tile < 24) { W = Wk; ld = 2048; cw0 = c0 - 4096; }
  else                { W = Wv; ld = 2048; cw0 = c0 - 6144; }
  const int kbase = ks * 192;
  const int cq = (threadIdx.x & 63) << 2;
  const int r0 = (threadIdx.x >> 6) * 10;
  __shared__ float h_lds[40][64];
  float acc[10][4];
#pragma unroll
  for (int r = 0; r < 10; ++r) { acc[r][0]=0.f; acc[r][1]=0.f; acc[r][2]=0.f; acc[r][3]=0.f; }
  for (int kc = 0; kc < 192; kc += 64) {
    __syncthreads();
    for (int i = threadIdx.x; i < 2560; i += 256) {
      int t = i >> 6, kk = i & 63;
      h_lds[t][kk] = hs[t * HID + kbase + kc + kk];
    }
    __syncthreads();
    const float* wp = W + (size_t)(kbase + kc) * ld + cw0 + cq;
#pragma unroll 2
    for (int k4 = 0; k4 < 16; ++k4) {
      float4 h4[10];
#pragma unroll
      for (int r = 0; r < 10; ++r)   // wave-uniform rows -> broadcast b128
        h4[r] = *reinterpret_cast<const float4*>(&h_lds[r0 + r][k4 << 2]);
#pragma unroll
      for (int j = 0; j < 4; ++j) {
        float4 w4 = *reinterpret_cast<const float4*>(wp + (size_t)((k4 << 2) + j) * ld);
#pragma unroll
        for (int r = 0; r < 10; ++r) {
          float hv = (j == 0) ? h4[r].x : (j == 1) ? h4[r].y
                   : (j == 2) ? h4[r].z : h4[r].w;
          acc[r][0] = fmaf(hv, w4.x, acc[r][0]);
          acc[r][1] = fmaf(hv, w4.y, acc[r][1]);
          acc[r][2] = fmaf(hv, w4.z, acc[r][2]);
          acc[r][3] = fmaf(hv, w4.w, acc[r][3]);
        }
      }
    }
  }
#pragma unroll
  for (int r = 0; r < 10; ++r) {
    int t = r0 + r;
    float4 v = make_float4(acc[r][0], acc[r][1], acc[r][2], acc[r][3]);
    *reinterpret_cast<float4*>(&part1[(size_t)(ks * TT + t) * QKV_COLS + c0 + cq]) = v;
  }
}

// ---------------- K2: k-split reduce + RoPE (r12 version) ----------------
// grid 1280 = 40 tokens * 32 tiles, block 256
__global__ __launch_bounds__(256) void k2_reduce_rope(
    const float* __restrict__ part1, const float* __restrict__ inv_freq,
    const int* __restrict__ pos_ids,
    float* __restrict__ qbuf, float* __restrict__ kbuf, float* __restrict__ vbuf) {
  const int t = blockIdx.x >> 5;
  const int tile = blockIdx.x & 31;
  const int c = (tile << 8) + threadIdx.x;
  float s = 0.f;
#pragma unroll
  for (int ks = 0; ks < 16; ++ks) s += part1[(size_t)(ks * TT + t) * QKV_COLS + c];
  __shared__ float sl[256];
  sl[threadIdx.x] = s;
  __syncthreads();
  if (tile < 24) {
    const int d = threadIdx.x;
    const int d2 = d & 127;
    float fr = (float)pos_ids[t] * inv_freq[d2];
    float cs = cosf(fr), sn = sinf(fr);
    float v = (d < 128) ? (sl[d] * cs - sl[d + 128] * sn)
                        : (sl[d] * cs + sl[d - 128] * sn);
    if (tile < 16) qbuf[t * 4096 + (tile << 8) + d] = v * 0.0625f;  // fold 1/sqrt(D)
    else           kbuf[t * 2048 + ((tile - 16) << 8) + d] = v;
  } else {
    vbuf[t * 2048 + ((tile - 24) << 8) + threadIdx.x] = s;
  }
}

// ---------------- K3 v12 (r12 exact + nq write guard) ----------------
// grid 1024 = b(16)*hk(8)*seg(8); block 256 = 4 waves, each wave owns one
// 64-token part (= one cache block). No block barriers after Q staging.
__global__ __launch_bounds__(256) void k3_attn_partial(
    const float* __restrict__ qbuf, const float* __restrict__ kbuf,
    const float* __restrict__ vbuf, const float* __restrict__ k_cache,
    const float* __restrict__ v_cache, const int* __restrict__ blk_off,
    const int* __restrict__ q_start, const int* __restrict__ q_lens,
    const int* __restrict__ kv_lens,
    float* __restrict__ part_o, float* __restrict__ part_ml) {
  const int seg = blockIdx.x & 7;
  const int hk = (blockIdx.x >> 3) & 7;
  const int b = blockIdx.x >> 6;
  const int kv_len = kv_lens[b];
  if ((seg << 8) >= kv_len) return;
  const int q_cnt = q_lens[b];
  const int hist = kv_len - q_cnt;
  const int q0 = q_start[b];
  const int nq = q_cnt * 2;

  __shared__ float q_lds[8][256];            //  8 KB (block-shared)
  __shared__ float S[4][2][64][8];           // 16 KB (wave-private slices)

  const int tid = threadIdx.x;
  const int w = tid >> 6;
  const int lane = tid & 63;

  for (int i = tid; i < 2048; i += 256) {
    int qv = i >> 8, d = i & 255;
    int qtok = min(qv >> 1, q_cnt - 1);
    q_lds[qv][d] = qbuf[(size_t)(q0 + qtok) * 4096 + (hk * Gn + (qv & 1)) * 256 + d];
  }
  __syncthreads();                           // the ONLY block barrier

  const int part = (seg << 2) + w;
  const int sBeg = part << 6;
  if (sBeg >= kv_len) return;

  const int blk = blk_off[(b << 5) + part];
  const float* kb   = k_cache + ((size_t)blk << 17) + ((size_t)hk << 8);
  const float* vb   = v_cache + ((size_t)blk << 17) + ((size_t)hk << 8);
  const float* knew = kbuf + ((size_t)q0 << 11) + ((size_t)hk << 8);
  const float* vnew = vbuf + ((size_t)q0 << 11) + ((size_t)hk << 8);

  const int tp = lane & 7;
  const int qd = lane >> 3;

  // ---- score: 2 passes x 32 tokens; 2-deep pipelined K loads ----
#pragma unroll
  for (int pass = 0; pass < 2; ++pass) {
    const float* kr[4];
#pragma unroll
    for (int tt = 0; tt < 4; ++tt) {
      int s = sBeg + (pass << 5) + (tp << 2) + tt;
      int sc = s < kv_len ? s : kv_len - 1;
      const float* row = (sc < hist) ? (kb + ((size_t)(sc & 63) << 11))
                                     : (knew + ((size_t)(sc - hist) << 11));
      kr[tt] = row + (qd << 2);
    }
    float acc[4][8];
#pragma unroll
    for (int tt = 0; tt < 4; ++tt)
#pragma unroll
      for (int qv = 0; qv < 8; ++qv) acc[tt][qv] = 0.f;

    float4 kf[2][4];
#pragma unroll
    for (int tt = 0; tt < 4; ++tt)
      kf[0][tt] = *reinterpret_cast<const float4*>(kr[tt]);
#pragma unroll
    for (int c = 0; c < 8; ++c) {
      if (c + 1 < 8) {                       // next chunk in flight under FMAs
#pragma unroll
        for (int tt = 0; tt < 4; ++tt)
          kf[(c + 1) & 1][tt] =
              *reinterpret_cast<const float4*>(kr[tt] + ((c + 1) << 5));
      }
      const float4* kc_ = kf[c & 1];
#pragma unroll
      for (int qv = 0; qv < 8; ++qv) {
        float4 qf = *reinterpret_cast<const float4*>(&q_lds[qv][(qd << 2) + (c << 5)]);
#pragma unroll
        for (int tt = 0; tt < 4; ++tt) {
          acc[tt][qv] = fmaf(qf.x, kc_[tt].x, acc[tt][qv]);
          acc[tt][qv] = fmaf(qf.y, kc_[tt].y, acc[tt][qv]);
          acc[tt][qv] = fmaf(qf.z, kc_[tt].z, acc[tt][qv]);
          acc[tt][qv] = fmaf(qf.w, kc_[tt].w, acc[tt][qv]);
        }
      }
    }
#pragma unroll
    for (int tt = 0; tt < 4; ++tt)
#pragma unroll
      for (int qv = 0; qv < 8; ++qv) {
        float v = acc[tt][qv];
        v += __shfl_xor(v, 8);
        v += __shfl_xor(v, 16);
        acc[tt][qv] = v;                     // half-sums at qd=0 (h0), qd=4 (h1)
      }
    if ((lane & 24) == 0) {
      const int h = lane >> 5;
#pragma unroll
      for (int tt = 0; tt < 4; ++tt) {
        int srel = (pass << 5) + (tp << 2) + tt;
        *reinterpret_cast<float4*>(&S[w][h][srel][0]) =
            make_float4(acc[tt][0], acc[tt][1], acc[tt][2], acc[tt][3]);
        *reinterpret_cast<float4*>(&S[w][h][srel][4]) =
            make_float4(acc[tt][4], acc[tt][5], acc[tt][6], acc[tt][7]);
      }
    }
  }
  WAVE_LDS_FENCE();

  // ---- wave-local softmax over 64 tokens x 8 qv ----
  const int qv2 = lane >> 3;
  const int grp = lane & 7;
  const int pidx8 = (((b * HKn + hk) * NPART + part) << 3);
  float sv[8];
  float mloc = -1e30f;
#pragma unroll
  for (int t = 0; t < 8; ++t) {
    int sl = (t << 3) + grp;
    float v = S[w][0][sl][qv2] + S[w][1][sl][qv2];
    int sAbs = sBeg + sl;
    bool valid = (qv2 < nq) && ((sAbs - hist) <= (qv2 >> 1));  // causal+tail
    v = valid ? v : -1e30f;
    sv[t] = v;
    mloc = fmaxf(mloc, v);
  }
  mloc = fmaxf(mloc, __shfl_xor(mloc, 1));
  mloc = fmaxf(mloc, __shfl_xor(mloc, 2));
  mloc = fmaxf(mloc, __shfl_xor(mloc, 4));
  const float M = mloc;
  float lloc = 0.f;
#pragma unroll
  for (int t = 0; t < 8; ++t) {
    float p = __expf(sv[t] - M);
    S[w][0][(t << 3) + grp][qv2] = p;        // p values in place
    lloc += p;
  }
  lloc += __shfl_xor(lloc, 1);
  lloc += __shfl_xor(lloc, 2);
  lloc += __shfl_xor(lloc, 4);
  if (grp == 0)
    *reinterpret_cast<float2*>(&part_ml[(size_t)(pidx8 + qv2) * 2]) =
        make_float2(M, lloc);
  WAVE_LDS_FENCE();

  // ---- PV: lane owns 4 dims; wave streams its own 64 V rows ----
  const int d4 = lane << 2;
  float4 pacc[8];
#pragma unroll
  for (int q = 0; q < 8; ++q) pacc[q] = make_float4(0.f, 0.f, 0.f, 0.f);
  const int lim = min(sBeg + 64, kv_len);

#define PV_STEP(VROW, SREL)                                          \
  {                                                                  \
    float4 vf = *reinterpret_cast<const float4*>(VROW);              \
    float4 p0 = *reinterpret_cast<const float4*>(&S[w][0][SREL][0]); \
    float4 p1 = *reinterpret_cast<const float4*>(&S[w][0][SREL][4]); \
    float pr[8] = {p0.x, p0.y, p0.z, p0.w, p1.x, p1.y, p1.z, p1.w};  \
    _Pragma("unroll")                                                \
    for (int q = 0; q < 8; ++q) {                                    \
      pacc[q].x = fmaf(pr[q], vf.x, pacc[q].x);                      \
      pacc[q].y = fmaf(pr[q], vf.y, pacc[q].y);                      \
      pacc[q].z = fmaf(pr[q], vf.z, pacc[q].z);                      \
      pacc[q].w = fmaf(pr[q], vf.w, pacc[q].w);                      \
    }                                                                \
  }

  {
    int eH = min(lim, hist);
#pragma unroll 4
    for (int s = sBeg; s < eH; ++s)
      PV_STEP(vb + ((size_t)(s & 63) << 11) + d4, s - sBeg);
    int bN = max(sBeg, hist);
    for (int s = bN; s < lim; ++s)
      PV_STEP(vnew + ((size_t)(s - hist) << 11) + d4, s - sBeg);
  }
#undef PV_STEP

#pragma unroll
  for (int q = 0; q < 8; ++q)
    if (q < nq)                              // wave-uniform: skip dead partials
      *reinterpret_cast<float4*>(&part_o[(size_t)(pidx8 + q) * 256 + d4]) = pacc[q];
}

// ---------------- K4 v2: combine part partials, 2 waves per unit ----------
// grid 1024 = b(16)*qtok(4)*h(16), block 128 (2 waves split parts -> merge)
__global__ __launch_bounds__(128) void k4_attn_reduce(
    const float* __restrict__ part_o, const float* __restrict__ part_ml,
    const int* __restrict__ q_start, const int* __restrict__ q_lens,
    const int* __restrict__ kv_lens, float* __restrict__ attn_out) {
  const int h = blockIdx.x & 15;
  const int qtok = (blockIdx.x >> 4) & 3;
  const int b = blockIdx.x >> 6;
  const int q_cnt = q_lens[b];
  if (qtok >= q_cnt) return;
  const int kv_len = kv_lens[b];
  const int nparts = (kv_len + 63) >> 6;
  const int qv = qtok * 2 + (h & 1);
  const int hk = h >> 1;
  const int w = threadIdx.x >> 6;
  const int lane = threadIdx.x & 63;
  const int pbase = ((b * HKn + hk) * NPART) << 3;

  __shared__ float o_sh[2][256];
  __shared__ float ml_sh[2][2];

  // wave w reduces parts w, w+2, w+4, ...
  float M = -1e30f;
  for (int i = w; i < nparts; i += 2)
    M = fmaxf(M, part_ml[(size_t)(pbase + (i << 3) + qv) * 2]);
  float4 o = make_float4(0.f, 0.f, 0.f, 0.f);
  float L = 0.f;
#pragma unroll 4
  for (int i = w; i < nparts; i += 2) {
    float2 ml = *reinterpret_cast<const float2*>(
        &part_ml[(size_t)(pbase + (i << 3) + qv) * 2]);
    float corr = __expf(ml.x - M);
    L += corr * ml.y;
    float4 pv = *reinterpret_cast<const float4*>(
        &part_o[(size_t)(pbase + (i << 3) + qv) * 256 + (lane << 2)]);
    o.x = fmaf(corr, pv.x, o.x);
    o.y = fmaf(corr, pv.y, o.y);
    o.z = fmaf(corr, pv.z, o.z);
    o.w = fmaf(corr, pv.w, o.w);
  }
  *reinterpret_cast<float4*>(&o_sh[w][lane << 2]) = o;
  if (lane == 0) { ml_sh[w][0] = M; ml_sh[w][1] = L; }
  __syncthreads();

  if (w == 0) {
    float M0 = ml_sh[0][0], M1 = ml_sh[1][0];
    float Mg = fmaxf(M0, M1);
    float e0 = __expf(M0 - Mg), e1 = __expf(M1 - Mg);
    float Lg = e0 * ml_sh[0][1] + e1 * ml_sh[1][1];
    float inv = 1.0f / Lg;
    float4 o0 = *reinterpret_cast<const float4*>(&o_sh[0][lane << 2]);
    float4 o1 = *reinterpret_cast<const float4*>(&o_sh[1][lane << 2]);
    float4 res = make_float4((e0 * o0.x + e1 * o1.x) * inv,
                             (e0 * o0.y + e1 * o1.y) * inv,
                             (e0 * o0.z + e1 * o1.z) * inv,
                             (e0 * o0.w + e1 * o1.w) * inv);
    int tr = q_start[b] + qtok;
    *reinterpret_cast<float4*>(&attn_out[((size_t)tr * HQn + h) * 256 + (lane << 2)]) = res;
  }
}

// ---------------- K5: output GEMM partial (r12 version) ----------------
// grid 384 = 12 col-tiles(256) * 32 k-splits(128), block 256; b128 h reads
__global__ __launch_bounds__(256) void k5_out_gemm(
    const float* __restrict__ ain, const float* __restrict__ Wo,
    float* __restrict__ part2) {
  const int tile = blockIdx.x % 12;
  const int ks = blockIdx.x / 12;
  const int c0 = tile << 8;
  const int kbase = ks << 7;
  const int cq = (threadIdx.x & 63) << 2;
  const int r0 = (threadIdx.x >> 6) * 10;
  __shared__ float h_lds[40][64];
  float acc[10][4];
#pragma unroll
  for (int r = 0; r < 10; ++r) { acc[r][0]=0.f; acc[r][1]=0.f; acc[r][2]=0.f; acc[r][3]=0.f; }
  for (int kc = 0; kc < 128; kc += 64) {
    __syncthreads();
    for (int i = threadIdx.x; i < 2560; i += 256) {
      int t = i >> 6, kk = i & 63;
      h_lds[t][kk] = ain[(size_t)t * 4096 + kbase + kc + kk];
    }
    __syncthreads();
    const float* wp = Wo + (size_t)(kbase + kc) * 3072 + c0 + cq;
#pragma unroll 2
    for (int k4 = 0; k4 < 16; ++k4) {
      float4 h4[10];
#pragma unroll
      for (int r = 0; r < 10; ++r)
        h4[r] = *reinterpret_cast<const float4*>(&h_lds[r0 + r][k4 << 2]);
#pragma unroll
      for (int j = 0; j < 4; ++j) {
        float4 w4 = *reinterpret_cast<const float4*>(wp + (size_t)((k4 << 2) + j) * 3072);
#pragma unroll
        for (int r = 0; r < 10; ++r) {
          float hv = (j == 0) ? h4[r].x : (j == 1) ? h4[r].y
                   : (j == 2) ? h4[r].z : h4[r].w;
          acc[r][0] = fmaf(hv, w4.x, acc[r][0]);
          acc[r][1] = fmaf(hv, w4.y, acc[r][1]);
          acc[r][2] = fmaf(hv, w4.z, acc[r][2]);
          acc[r][3] = fmaf(hv, w4.w, acc[r][3]);
        }
      }
    }
  }
#pragma unroll
  for (int r = 0; r < 10; ++r) {
    int t = r0 + r;
    float4 v = make_float4(acc[r][0], acc[r][1], acc[r][2], acc[r][3]);
    *reinterpret_cast<float4*>(&part2[(size_t)(ks * TT + t) * 3072 + c0 + cq]) = v;
  }
}

// ---------------- K6: final k-split reduce -> d_out ----------------
// grid 480, block 256  (40*3072 = 122880 outputs)
__global__ __launch_bounds__(256) void k6_final_reduce(
    const float* __restrict__ part2, float* __restrict__ out) {
  const int idx = blockIdx.x * 256 + threadIdx.x;
  float s = 0.f;
#pragma unroll
  for (int ks = 0; ks < 32; ++ks) s += part2[(size_t)ks * 122880 + idx];
  out[idx] = s;
}

extern "C" void kernel_launch(void* const* d_in, const int* in_sizes, int n_in,
                              void* d_out, int out_size, void* d_ws, size_t ws_size,
                              hipStream_t stream) {
  const float* hs       = (const float*)d_in[0];
  const float* Wq       = (const float*)d_in[1];
  const float* Wk       = (const float*)d_in[2];
  const float* Wv       = (const float*)d_in[3];
  const float* Wo       = (const float*)d_in[4];
  const float* k_cache  = (const float*)d_in[5];
  const float* v_cache  = (const float*)d_in[6];
  const float* inv_freq = (const float*)d_in[7];
  const int*   pos_ids  = (const int*)d_in[8];
  const int*   q_start  = (const int*)d_in[9];
  const int*   q_lens   = (const int*)d_in[10];
  const int*   kv_lens  = (const int*)d_in[11];
  const int*   blk_off  = (const int*)d_in[12];

  float* ws = (float*)d_ws;
  float* qbuf     = ws;                  // 163,840
  float* kbuf     = ws + 163840;         //  81,920
  float* vbuf     = ws + 245760;         //  81,920
  float* attn_out = ws + 327680;         // 163,840
  float* part1    = ws + 491520;         // 5,242,880  (k1/k2 only)
  float* part_o   = ws + 5734400;        // 8,388,608  (128*32*8*256)
  float* part_ml  = ws + 14123008;       //    65,536
  float* part2    = ws + 14188544;       // 3,932,160  (k5/k6)
  float* out      = (float*)d_out;

  k1_qkv_gemm<<<512, 256, 0, stream>>>(hs, Wq, Wk, Wv, part1);
  k2_reduce_rope<<<1280, 256, 0, stream>>>(part1, inv_freq, pos_ids, qbuf, kbuf, vbuf);
  k3_attn_partial<<<1024, 256, 0, stream>>>(qbuf, kbuf, vbuf, k_cache, v_cache,
                                            blk_off, q_start, q_lens, kv_lens,
                                            part_o, part_ml);
  k4_attn_reduce<<<1024, 128, 0, stream>>>(part_o, part_ml, q_start, q_lens,
                                           kv_lens, attn_out);
  k5_out_gemm<<<384, 256, 0, stream>>>(attn_out, Wo, part2);
  k6_final_reduce<<<480, 256, 0, stream>>>(part2, out);
}

// Round 16
// 244.866 us; speedup vs baseline: 1.0995x; 1.0153x over previous
//
#include <hip/hip_runtime.h>
#include <math.h>

#define TT 40          // total query tokens (sum of q_seqlens)
#define NB 16          // batch
#define HQn 16         // query heads
#define HKn 8          // kv heads
#define Gn 2           // GQA group
#define Dn 256         // head dim
#define HID 3072
#define QKV_COLS 8192  // 4096 + 2048 + 2048
#define NPART 32       // 64-token parts per sequence (2048/64)

// intra-wave LDS handoff fence (guide rule #18)
#define WAVE_LDS_FENCE() do { \
    asm volatile("s_waitcnt lgkmcnt(0)" ::: "memory"); \
    __builtin_amdgcn_sched_barrier(0); \
  } while (0)

// ---------------- K1: QKV partial GEMM (r12 version) ----------------
// grid 512 = 32 col-tiles(256) * 16 k-splits(192), block 256
__global__ __launch_bounds__(256) void k1_qkv_gemm(
    const float* __restrict__ hs, const float* __restrict__ Wq,
    const float* __restrict__ Wk, const float* __restrict__ Wv,
    float* __restrict__ part1) {
  const int tile = blockIdx.x & 31;
  const int ks = blockIdx.x >> 5;
  const int c0 = tile << 8;
  const float* W; int ld, cw0;
  if (tile < 16)      { W = Wq; ld = 4096; cw0 = c0; }
  else if (tile < 24) { W = Wk; ld = 2048; cw0 = c0 - 4096; }
  else                { W = Wv; ld = 2048; cw0 = c0 - 6144; }
  const int kbase = ks * 192;
  const int cq = (threadIdx.x & 63) << 2;
  const int r0 = (threadIdx.x >> 6) * 10;
  __shared__ float h_lds[40][64];
  float acc[10][4];
#pragma unroll
  for (int r = 0; r < 10; ++r) { acc[r][0]=0.f; acc[r][1]=0.f; acc[r][2]=0.f; acc[r][3]=0.f; }
  for (int kc = 0; kc < 192; kc += 64) {
    __syncthreads();
    for (int i = threadIdx.x; i < 2560; i += 256) {
      int t = i >> 6, kk = i & 63;
      h_lds[t][kk] = hs[t * HID + kbase + kc + kk];
    }
    __syncthreads();
    const float* wp = W + (size_t)(kbase + kc) * ld + cw0 + cq;
#pragma unroll 2
    for (int k4 = 0; k4 < 16; ++k4) {
      float4 h4[10];
#pragma unroll
      for (int r = 0; r < 10; ++r)   // wave-uniform rows -> broadcast b128
        h4[r] = *reinterpret_cast<const float4*>(&h_lds[r0 + r][k4 << 2]);
#pragma unroll
      for (int j = 0; j < 4; ++j) {
        float4 w4 = *reinterpret_cast<const float4*>(wp + (size_t)((k4 << 2) + j) * ld);
#pragma unroll
        for (int r = 0; r < 10; ++r) {
          float hv = (j == 0) ? h4[r].x : (j == 1) ? h4[r].y
                   : (j == 2) ? h4[r].z : h4[r].w;
          acc[r][0] = fmaf(hv, w4.x, acc[r][0]);
          acc[r][1] = fmaf(hv, w4.y, acc[r][1]);
          acc[r][2] = fmaf(hv, w4.z, acc[r][2]);
          acc[r][3] = fmaf(hv, w4.w, acc[r][3]);
        }
      }
    }
  }
#pragma unroll
  for (int r = 0; r < 10; ++r) {
    int t = r0 + r;
    float4 v = make_float4(acc[r][0], acc[r][1], acc[r][2], acc[r][3]);
    *reinterpret_cast<float4*>(&part1[(size_t)(ks * TT + t) * QKV_COLS + c0 + cq]) = v;
  }
}

// ---------------- K2: k-split reduce + RoPE (r12 version) ----------------
// grid 1280 = 40 tokens * 32 tiles, block 256
__global__ __launch_bounds__(256) void k2_reduce_rope(
    const float* __restrict__ part1, const float* __restrict__ inv_freq,
    const int* __restrict__ pos_ids,
    float* __restrict__ qbuf, float* __restrict__ kbuf, float* __restrict__ vbuf) {
  const int t = blockIdx.x >> 5;
  const int tile = blockIdx.x & 31;
  const int c = (tile << 8) + threadIdx.x;
  float s = 0.f;
#pragma unroll
  for (int ks = 0; ks < 16; ++ks) s += part1[(size_t)(ks * TT + t) * QKV_COLS + c];
  __shared__ float sl[256];
  sl[threadIdx.x] = s;
  __syncthreads();
  if (tile < 24) {
    const int d = threadIdx.x;
    const int d2 = d & 127;
    float fr = (float)pos_ids[t] * inv_freq[d2];
    float cs = cosf(fr), sn = sinf(fr);
    float v = (d < 128) ? (sl[d] * cs - sl[d + 128] * sn)
                        : (sl[d] * cs + sl[d - 128] * sn);
    if (tile < 16) qbuf[t * 4096 + (tile << 8) + d] = v * 0.0625f;  // fold 1/sqrt(D)
    else           kbuf[t * 2048 + ((tile - 16) << 8) + d] = v;
  } else {
    vbuf[t * 2048 + ((tile - 24) << 8) + threadIdx.x] = s;
  }
}

// ---------------- K3 v16: r15 + PV quad ping-pong hot path ----------------
// grid 1024 = b(16)*hk(8)*seg(8); block 256 = 4 waves, each wave owns one
// 64-token part (= one cache block). No block barriers after Q staging.
__global__ __launch_bounds__(256) void k3_attn_partial(
    const float* __restrict__ qbuf, const float* __restrict__ kbuf,
    const float* __restrict__ vbuf, const float* __restrict__ k_cache,
    const float* __restrict__ v_cache, const int* __restrict__ blk_off,
    const int* __restrict__ q_start, const int* __restrict__ q_lens,
    const int* __restrict__ kv_lens,
    float* __restrict__ part_o, float* __restrict__ part_ml) {
  const int seg = blockIdx.x & 7;
  const int hk = (blockIdx.x >> 3) & 7;
  const int b = blockIdx.x >> 6;
  const int kv_len = kv_lens[b];
  if ((seg << 8) >= kv_len) return;
  const int q_cnt = q_lens[b];
  const int hist = kv_len - q_cnt;
  const int q0 = q_start[b];
  const int nq = q_cnt * 2;

  __shared__ float q_lds[8][256];            //  8 KB (block-shared)
  __shared__ float S[4][2][64][8];           // 16 KB (wave-private slices)

  const int tid = threadIdx.x;
  const int w = tid >> 6;
  const int lane = tid & 63;

  for (int i = tid; i < 2048; i += 256) {
    int qv = i >> 8, d = i & 255;
    int qtok = min(qv >> 1, q_cnt - 1);
    q_lds[qv][d] = qbuf[(size_t)(q0 + qtok) * 4096 + (hk * Gn + (qv & 1)) * 256 + d];
  }
  __syncthreads();                           // the ONLY block barrier

  const int part = (seg << 2) + w;
  const int sBeg = part << 6;
  if (sBeg >= kv_len) return;

  const int blk = blk_off[(b << 5) + part];
  const float* kb   = k_cache + ((size_t)blk << 17) + ((size_t)hk << 8);
  const float* vb   = v_cache + ((size_t)blk << 17) + ((size_t)hk << 8);
  const float* knew = kbuf + ((size_t)q0 << 11) + ((size_t)hk << 8);
  const float* vnew = vbuf + ((size_t)q0 << 11) + ((size_t)hk << 8);

  const int tp = lane & 7;
  const int qd = lane >> 3;

  // ---- score: 2 passes x 32 tokens; 2-deep pipelined K loads ----
#pragma unroll
  for (int pass = 0; pass < 2; ++pass) {
    const float* kr[4];
#pragma unroll
    for (int tt = 0; tt < 4; ++tt) {
      int s = sBeg + (pass << 5) + (tp << 2) + tt;
      int sc = s < kv_len ? s : kv_len - 1;
      const float* row = (sc < hist) ? (kb + ((size_t)(sc & 63) << 11))
                                     : (knew + ((size_t)(sc - hist) << 11));
      kr[tt] = row + (qd << 2);
    }
    float acc[4][8];
#pragma unroll
    for (int tt = 0; tt < 4; ++tt)
#pragma unroll
      for (int qv = 0; qv < 8; ++qv) acc[tt][qv] = 0.f;

    float4 kf[2][4];
#pragma unroll
    for (int tt = 0; tt < 4; ++tt)
      kf[0][tt] = *reinterpret_cast<const float4*>(kr[tt]);
#pragma unroll
    for (int c = 0; c < 8; ++c) {
      if (c + 1 < 8) {                       // next chunk in flight under FMAs
#pragma unroll
        for (int tt = 0; tt < 4; ++tt)
          kf[(c + 1) & 1][tt] =
              *reinterpret_cast<const float4*>(kr[tt] + ((c + 1) << 5));
      }
      const float4* kc_ = kf[c & 1];
#pragma unroll
      for (int qv = 0; qv < 8; ++qv) {
        float4 qf = *reinterpret_cast<const float4*>(&q_lds[qv][(qd << 2) + (c << 5)]);
#pragma unroll
        for (int tt = 0; tt < 4; ++tt) {
          acc[tt][qv] = fmaf(qf.x, kc_[tt].x, acc[tt][qv]);
          acc[tt][qv] = fmaf(qf.y, kc_[tt].y, acc[tt][qv]);
          acc[tt][qv] = fmaf(qf.z, kc_[tt].z, acc[tt][qv]);
          acc[tt][qv] = fmaf(qf.w, kc_[tt].w, acc[tt][qv]);
        }
      }
    }
#pragma unroll
    for (int tt = 0; tt < 4; ++tt)
#pragma unroll
      for (int qv = 0; qv < 8; ++qv) {
        float v = acc[tt][qv];
        v += __shfl_xor(v, 8);
        v += __shfl_xor(v, 16);
        acc[tt][qv] = v;                     // half-sums at qd=0 (h0), qd=4 (h1)
      }
    if ((lane & 24) == 0) {
      const int h = lane >> 5;
#pragma unroll
      for (int tt = 0; tt < 4; ++tt) {
        int srel = (pass << 5) + (tp << 2) + tt;
        *reinterpret_cast<float4*>(&S[w][h][srel][0]) =
            make_float4(acc[tt][0], acc[tt][1], acc[tt][2], acc[tt][3]);
        *reinterpret_cast<float4*>(&S[w][h][srel][4]) =
            make_float4(acc[tt][4], acc[tt][5], acc[tt][6], acc[tt][7]);
      }
    }
  }
  WAVE_LDS_FENCE();

  // ---- wave-local softmax over 64 tokens x 8 qv ----
  const int qv2 = lane >> 3;
  const int grp = lane & 7;
  const int pidx8 = (((b * HKn + hk) * NPART + part) << 3);
  float sv[8];
  float mloc = -1e30f;
#pragma unroll
  for (int t = 0; t < 8; ++t) {
    int sl = (t << 3) + grp;
    float v = S[w][0][sl][qv2] + S[w][1][sl][qv2];
    int sAbs = sBeg + sl;
    bool valid = (qv2 < nq) && ((sAbs - hist) <= (qv2 >> 1));  // causal+tail
    v = valid ? v : -1e30f;
    sv[t] = v;
    mloc = fmaxf(mloc, v);
  }
  mloc = fmaxf(mloc, __shfl_xor(mloc, 1));
  mloc = fmaxf(mloc, __shfl_xor(mloc, 2));
  mloc = fmaxf(mloc, __shfl_xor(mloc, 4));
  const float M = mloc;
  float lloc = 0.f;
#pragma unroll
  for (int t = 0; t < 8; ++t) {
    float p = __expf(sv[t] - M);
    S[w][0][(t << 3) + grp][qv2] = p;        // p values in place
    lloc += p;
  }
  lloc += __shfl_xor(lloc, 1);
  lloc += __shfl_xor(lloc, 2);
  lloc += __shfl_xor(lloc, 4);
  if (grp == 0)
    *reinterpret_cast<float2*>(&part_ml[(size_t)(pidx8 + qv2) * 2]) =
        make_float2(M, lloc);
  WAVE_LDS_FENCE();

  // ---- PV: lane owns 4 dims; wave streams its own 64 V rows ----
  const int d4 = lane << 2;
  float4 pacc[8];
#pragma unroll
  for (int q = 0; q < 8; ++q) pacc[q] = make_float4(0.f, 0.f, 0.f, 0.f);
  const int lim = min(sBeg + 64, kv_len);

#define PV_BODY(VF, SREL)                                            \
  {                                                                  \
    float4 vf = (VF);                                                \
    float4 p0 = *reinterpret_cast<const float4*>(&S[w][0][SREL][0]); \
    float4 p1 = *reinterpret_cast<const float4*>(&S[w][0][SREL][4]); \
    float pr[8] = {p0.x, p0.y, p0.z, p0.w, p1.x, p1.y, p1.z, p1.w};  \
    _Pragma("unroll")                                                \
    for (int q = 0; q < 8; ++q) {                                    \
      pacc[q].x = fmaf(pr[q], vf.x, pacc[q].x);                      \
      pacc[q].y = fmaf(pr[q], vf.y, pacc[q].y);                      \
      pacc[q].z = fmaf(pr[q], vf.z, pacc[q].z);                      \
      pacc[q].w = fmaf(pr[q], vf.w, pacc[q].w);                      \
    }                                                                \
  }

  {
    const int eH = min(lim, hist);
    if (eH - sBeg == 64) {
      // hot path: full-history part. Quad ping-pong: 2 banks x 4 rows,
      // 8 rows (4KB/wave) in flight; refill a bank right after its last use.
      const float* vbase = vb + d4;
      float4 VA[4], VB[4];
#pragma unroll
      for (int t = 0; t < 4; ++t)
        VA[t] = *reinterpret_cast<const float4*>(vbase + ((size_t)t << 11));
#pragma unroll
      for (int t = 0; t < 4; ++t)
        VB[t] = *reinterpret_cast<const float4*>(vbase + ((size_t)(t + 4) << 11));
#pragma unroll
      for (int g = 0; g < 16; ++g) {
        float4* bank = (g & 1) ? VB : VA;
        const int base = g << 2;
        PV_BODY(bank[0], base);
        PV_BODY(bank[1], base + 1);
        PV_BODY(bank[2], base + 2);
        PV_BODY(bank[3], base + 3);
        if (g + 2 < 16) {                    // refill this bank with rows +8
#pragma unroll
          for (int t = 0; t < 4; ++t)
            bank[t] = *reinterpret_cast<const float4*>(
                vbase + ((size_t)(base + 8 + t) << 11));
        }
      }
    } else {
      // boundary/tail parts: generic path (r15)
#pragma unroll 4
      for (int s = sBeg; s < eH; ++s)
        PV_BODY(*reinterpret_cast<const float4*>(
                    vb + ((size_t)(s & 63) << 11) + d4), s - sBeg);
      int bN = max(sBeg, hist);
      for (int s = bN; s < lim; ++s)
        PV_BODY(*reinterpret_cast<const float4*>(
                    vnew + ((size_t)(s - hist) << 11) + d4), s - sBeg);
    }
  }
#undef PV_BODY

#pragma unroll
  for (int q = 0; q < 8; ++q)
    if (q < nq)                              // wave-uniform: skip dead partials
      *reinterpret_cast<float4*>(&part_o[(size_t)(pidx8 + q) * 256 + d4]) = pacc[q];
}

// ---------------- K4 v2: combine part partials, 2 waves per unit ----------
// grid 1024 = b(16)*qtok(4)*h(16), block 128 (2 waves split parts -> merge)
__global__ __launch_bounds__(128) void k4_attn_reduce(
    const float* __restrict__ part_o, const float* __restrict__ part_ml,
    const int* __restrict__ q_start, const int* __restrict__ q_lens,
    const int* __restrict__ kv_lens, float* __restrict__ attn_out) {
  const int h = blockIdx.x & 15;
  const int qtok = (blockIdx.x >> 4) & 3;
  const int b = blockIdx.x >> 6;
  const int q_cnt = q_lens[b];
  if (qtok >= q_cnt) return;
  const int kv_len = kv_lens[b];
  const int nparts = (kv_len + 63) >> 6;
  const int qv = qtok * 2 + (h & 1);
  const int hk = h >> 1;
  const int w = threadIdx.x >> 6;
  const int lane = threadIdx.x & 63;
  const int pbase = ((b * HKn + hk) * NPART) << 3;

  __shared__ float o_sh[2][256];
  __shared__ float ml_sh[2][2];

  // wave w reduces parts w, w+2, w+4, ...
  float M = -1e30f;
  for (int i = w; i < nparts; i += 2)
    M = fmaxf(M, part_ml[(size_t)(pbase + (i << 3) + qv) * 2]);
  float4 o = make_float4(0.f, 0.f, 0.f, 0.f);
  float L = 0.f;
#pragma unroll 4
  for (int i = w; i < nparts; i += 2) {
    float2 ml = *reinterpret_cast<const float2*>(
        &part_ml[(size_t)(pbase + (i << 3) + qv) * 2]);
    float corr = __expf(ml.x - M);
    L += corr * ml.y;
    float4 pv = *reinterpret_cast<const float4*>(
        &part_o[(size_t)(pbase + (i << 3) + qv) * 256 + (lane << 2)]);
    o.x = fmaf(corr, pv.x, o.x);
    o.y = fmaf(corr, pv.y, o.y);
    o.z = fmaf(corr, pv.z, o.z);
    o.w = fmaf(corr, pv.w, o.w);
  }
  *reinterpret_cast<float4*>(&o_sh[w][lane << 2]) = o;
  if (lane == 0) { ml_sh[w][0] = M; ml_sh[w][1] = L; }
  __syncthreads();

  if (w == 0) {
    float M0 = ml_sh[0][0], M1 = ml_sh[1][0];
    float Mg = fmaxf(M0, M1);
    float e0 = __expf(M0 - Mg), e1 = __expf(M1 - Mg);
    float Lg = e0 * ml_sh[0][1] + e1 * ml_sh[1][1];
    float inv = 1.0f / Lg;
    float4 o0 = *reinterpret_cast<const float4*>(&o_sh[0][lane << 2]);
    float4 o1 = *reinterpret_cast<const float4*>(&o_sh[1][lane << 2]);
    float4 res = make_float4((e0 * o0.x + e1 * o1.x) * inv,
                             (e0 * o0.y + e1 * o1.y) * inv,
                             (e0 * o0.z + e1 * o1.z) * inv,
                             (e0 * o0.w + e1 * o1.w) * inv);
    int tr = q_start[b] + qtok;
    *reinterpret_cast<float4*>(&attn_out[((size_t)tr * HQn + h) * 256 + (lane << 2)]) = res;
  }
}

// ---------------- K5: output GEMM partial (r12 version) ----------------
// grid 384 = 12 col-tiles(256) * 32 k-splits(128), block 256; b128 h reads
__global__ __launch_bounds__(256) void k5_out_gemm(
    const float* __restrict__ ain, const float* __restrict__ Wo,
    float* __restrict__ part2) {
  const int tile = blockIdx.x % 12;
  const int ks = blockIdx.x / 12;
  const int c0 = tile << 8;
  const int kbase = ks << 7;
  const int cq = (threadIdx.x & 63) << 2;
  const int r0 = (threadIdx.x >> 6) * 10;
  __shared__ float h_lds[40][64];
  float acc[10][4];
#pragma unroll
  for (int r = 0; r < 10; ++r) { acc[r][0]=0.f; acc[r][1]=0.f; acc[r][2]=0.f; acc[r][3]=0.f; }
  for (int kc = 0; kc < 128; kc += 64) {
    __syncthreads();
    for (int i = threadIdx.x; i < 2560; i += 256) {
      int t = i >> 6, kk = i & 63;
      h_lds[t][kk] = ain[(size_t)t * 4096 + kbase + kc + kk];
    }
    __syncthreads();
    const float* wp = Wo + (size_t)(kbase + kc) * 3072 + c0 + cq;
#pragma unroll 2
    for (int k4 = 0; k4 < 16; ++k4) {
      float4 h4[10];
#pragma unroll
      for (int r = 0; r < 10; ++r)
        h4[r] = *reinterpret_cast<const float4*>(&h_lds[r0 + r][k4 << 2]);
#pragma unroll
      for (int j = 0; j < 4; ++j) {
        float4 w4 = *reinterpret_cast<const float4*>(wp + (size_t)((k4 << 2) + j) * 3072);
#pragma unroll
        for (int r = 0; r < 10; ++r) {
          float hv = (j == 0) ? h4[r].x : (j == 1) ? h4[r].y
                   : (j == 2) ? h4[r].z : h4[r].w;
          acc[r][0] = fmaf(hv, w4.x, acc[r][0]);
          acc[r][1] = fmaf(hv, w4.y, acc[r][1]);
          acc[r][2] = fmaf(hv, w4.z, acc[r][2]);
          acc[r][3] = fmaf(hv, w4.w, acc[r][3]);
        }
      }
    }
  }
#pragma unroll
  for (int r = 0; r < 10; ++r) {
    int t = r0 + r;
    float4 v = make_float4(acc[r][0], acc[r][1], acc[r][2], acc[r][3]);
    *reinterpret_cast<float4*>(&part2[(size_t)(ks * TT + t) * 3072 + c0 + cq]) = v;
  }
}

// ---------------- K6: final k-split reduce -> d_out ----------------
// grid 480, block 256  (40*3072 = 122880 outputs)
__global__ __launch_bounds__(256) void k6_final_reduce(
    const float* __restrict__ part2, float* __restrict__ out) {
  const int idx = blockIdx.x * 256 + threadIdx.x;
  float s = 0.f;
#pragma unroll
  for (int ks = 0; ks < 32; ++ks) s += part2[(size_t)ks * 122880 + idx];
  out[idx] = s;
}

extern "C" void kernel_launch(void* const* d_in, const int* in_sizes, int n_in,
                              void* d_out, int out_size, void* d_ws, size_t ws_size,
                              hipStream_t stream) {
  const float* hs       = (const float*)d_in[0];
  const float* Wq       = (const float*)d_in[1];
  const float* Wk       = (const float*)d_in[2];
  const float* Wv       = (const float*)d_in[3];
  const float* Wo       = (const float*)d_in[4];
  const float* k_cache  = (const float*)d_in[5];
  const float* v_cache  = (const float*)d_in[6];
  const float* inv_freq = (const float*)d_in[7];
  const int*   pos_ids  = (const int*)d_in[8];
  const int*   q_start  = (const int*)d_in[9];
  const int*   q_lens   = (const int*)d_in[10];
  const int*   kv_lens  = (const int*)d_in[11];
  const int*   blk_off  = (const int*)d_in[12];

  float* ws = (float*)d_ws;
  float* qbuf     = ws;                  // 163,840
  float* kbuf     = ws + 163840;         //  81,920
  float* vbuf     = ws + 245760;         //  81,920
  float* attn_out = ws + 327680;         // 163,840
  float* part1    = ws + 491520;         // 5,242,880  (k1/k2 only)
  float* part_o   = ws + 5734400;        // 8,388,608  (128*32*8*256)
  float* part_ml  = ws + 14123008;       //    65,536
  float* part2    = ws + 14188544;       // 3,932,160  (k5/k6)
  float* out      = (float*)d_out;

  k1_qkv_gemm<<<512, 256, 0, stream>>>(hs, Wq, Wk, Wv, part1);
  k2_reduce_rope<<<1280, 256, 0, stream>>>(part1, inv_freq, pos_ids, qbuf, kbuf, vbuf);
  k3_attn_partial<<<1024, 256, 0, stream>>>(qbuf, kbuf, vbuf, k_cache, v_cache,
                                            blk_off, q_start, q_lens, kv_lens,
                                            part_o, part_ml);
  k4_attn_reduce<<<1024, 128, 0, stream>>>(part_o, part_ml, q_start, q_lens,
                                           kv_lens, attn_out);
  k5_out_gemm<<<384, 256, 0, stream>>>(attn_out, Wo, part2);
  k6_final_reduce<<<480, 256, 0, stream>>>(part2, out);
}